// Round 7
// baseline (254.912 us; speedup 1.0000x reference)
//
#include <hip/hip_runtime.h>

// VectorQuantizer: x (64,64,64,64) f32, embeddings (64,512) f32
// rows N = 64^3 = 262144, D = 64, K = 512
// out: quantized_st (16777216 f32) ++ loss (1 f32)
//
// Round 7: fp16 2-term-split MFMA main (A = z_hi+z_lo fp16, B = e_hi fp16)
// + near-tie flagging (12-grid-step window) + bit-exact numpy-emulation
// fixup (absmax 0.0 verified rounds 2-6).
//  - vq_main: ONE 32x32 tile per wave (was two) -> fewer regs, 2x waves,
//    better latency hiding. Grid 2048 x 256.
//  - vq_fixup: 8 flagged rows per wave -> E read once per 8 rows (was once
//    per row = ~1.7 GB L2 traffic at ~13k flags). z register-distributed,
//    broadcast via shfl; numpy emulation instruction-identical.

typedef __attribute__((ext_vector_type(8))) _Float16 f16x8;
typedef __attribute__((ext_vector_type(16))) float f32x16;

#define NROWS   262144
#define DIM     64
#define KCODES  512
#define NELEM   16777216
#define LISTCAP 65536

// ws layout (float offsets)
#define WS_ET     0        // 512*64 code-major embeddings
#define WS_EN     32768    // exact enorm (numpy rounding)
#define WS_EN8    33280    // enorm + 8 (approx domain, keeps d positive)
#define WS_PACKH  33792    // uint4[4096]: e_hi fp16 B-fragments
#define WS_CNT    50176    // flag counter (int)
#define WS_LIST   50192    // flagged rows: (row<<9)|idx

union FragH { uint4 q; f16x8 v; _Float16 u[8]; };

// ---- prep: ET transpose, exact enorm (R(e*e) + sequential adds), enorm+8,
// zero loss + flag counter.
__global__ void vq_prep(const float* __restrict__ E, float* __restrict__ ET,
                        float* __restrict__ en, float* __restrict__ en8,
                        float* __restrict__ loss, int* __restrict__ cnt) {
    int k = blockIdx.x * blockDim.x + threadIdx.x;   // 0..511
    if (k == 0) *loss = 0.f;
    if (k == 1) *cnt = 0;
    float s = 0.f;
    for (int i = 0; i < DIM; ++i) {
        float v = E[i * KCODES + k];
        ET[k * DIM + i] = v;
        s = __fadd_rn(s, __fmul_rn(v, v));
    }
    en[k] = s;
    en8[k] = __fadd_rn(s, 8.0f);
}

// ---- pack e_hi (fp16 RNE) into 32x32x16 B-fragment order:
// frag id = (t*4+c)*64+lane holds B[k = c*16+(lane>>5)*8+j][n = t*32+(lane&31)]
__global__ void vq_pack(const float* __restrict__ E, uint4* __restrict__ packH) {
    const int id = blockIdx.x * 256 + threadIdx.x;   // 0..4095
    const int lane = id & 63;
    const int c = (id >> 6) & 3;
    const int t = id >> 8;
    const int n = t * 32 + (lane & 31);
    const int kb = c * 16 + (lane >> 5) * 8;
    FragH H;
    #pragma unroll
    for (int j = 0; j < 8; ++j)
        H.u[j] = (_Float16)E[(size_t)(kb + j) * KCODES + n];
    packH[id] = H.q;
}

// ---- main: 4 waves x 32 rows = 128 rows/block, grid 2048. No LDS.
// Each wave: ONE 32x32 M-tile over 16 col-tiles; 8 MFMA per t.
__global__ __launch_bounds__(256)
void vq_main(const float* __restrict__ x, const float* __restrict__ ET,
             const float* __restrict__ en8, const uint4* __restrict__ packH,
             float* __restrict__ outp, float* __restrict__ loss,
             int* __restrict__ cnt, int* __restrict__ list) {
    const int tid  = threadIdx.x;
    const int wv   = tid >> 6;
    const int lane = tid & 63;
    const int h    = lane >> 5;
    const int l31  = lane & 31;
    const size_t rowbase = (size_t)blockIdx.x * 128 + (size_t)wv * 32;

    // A fragments: fp16 split z = zh + zl; A[m=lane&31][k=c*16+h*8+j]
    FragH ah[4], al[4];
    {
        const float* xr = x + (rowbase + l31) * DIM;
        #pragma unroll
        for (int c = 0; c < 4; ++c) {
            const float* xp = xr + c * 16 + h * 8;
            float4 p0 = *(const float4*)xp;
            float4 p1 = *(const float4*)(xp + 4);
            float vv[8] = {p0.x, p0.y, p0.z, p0.w, p1.x, p1.y, p1.z, p1.w};
            #pragma unroll
            for (int j = 0; j < 8; ++j) {
                _Float16 hh = (_Float16)vv[j];
                ah[c].u[j] = hh;
                al[c].u[j] = (_Float16)(vv[j] - (float)hh);
            }
        }
    }

    unsigned int b1[16], b2[16];                     // per-row-slot top-2 keys
    #pragma unroll
    for (int r = 0; r < 16; ++r) { b1[r] = 0xFFFFFFFFu; b2[r] = 0xFFFFFFFFu; }

    // Register double-buffer: prefetch t+1's B-fragments before t's MFMAs.
    FragH bh[4], bn[4];
    #pragma unroll
    for (int c = 0; c < 4; ++c) bh[c].q = packH[c * 64 + lane];

    for (int t = 0; t < 16; ++t) {
        const float en8v = en8[t * 32 + l31];        // issued early, MFMA-covered
        if (t < 15) {
            #pragma unroll
            for (int c = 0; c < 4; ++c)
                bn[c].q = packH[((t + 1) * 4 + c) * 64 + lane];   // L1/L2-hot
        }
        f32x16 A0;
        #pragma unroll
        for (int r = 0; r < 16; ++r) A0[r] = 0.f;
        #pragma unroll
        for (int c = 0; c < 4; ++c)                      // z_hi * e_hi
            A0 = __builtin_amdgcn_mfma_f32_32x32x16_f16(ah[c].v, bh[c].v, A0, 0, 0, 0);
        #pragma unroll
        for (int c = 0; c < 4; ++c)                      // z_lo * e_hi
            A0 = __builtin_amdgcn_mfma_f32_32x32x16_f16(al[c].v, bh[c].v, A0, 0, 0, 0);
        // keys: d = enorm+8 - 2*sim > 0; (bits & ~511) | col sorts by dist
        const unsigned int colv = (unsigned int)(t * 32 + l31);
        #pragma unroll
        for (int r = 0; r < 16; ++r) {
            float d = fmaf(-2.f, A0[r], en8v);
            unsigned int key = (__float_as_uint(d) & 0xFFFFFE00u) | colv;
            unsigned int n1 = min(key, b1[r]);
            unsigned int mx = max(key, b1[r]);
            b2[r] = min(b2[r], mx);
            b1[r] = n1;
        }
        #pragma unroll
        for (int c = 0; c < 4; ++c) bh[c] = bn[c];
    }

    // merge top-2 across the 32-lane half-group; C row = (r&3)+8*(r>>2)+4*h
    float lsq = 0.f;
    #pragma unroll
    for (int r = 0; r < 16; ++r) {
        unsigned int B1 = b1[r], B2 = b2[r];
        #pragma unroll
        for (int off = 1; off <= 16; off <<= 1) {
            unsigned int o1 = (unsigned int)__shfl_xor((int)B1, off, 64);
            unsigned int o2 = (unsigned int)__shfl_xor((int)B2, off, 64);
            unsigned int n1 = min(B1, o1);
            unsigned int mx = max(B1, o1);
            B2 = min(min(B2, o2), mx);
            B1 = n1;
        }
        const int idx = (int)(B1 & 511u);
        const int rowl = (r & 3) + 8 * (r >> 2) + 4 * h;
        const size_t row = rowbase + rowl;
        // 12-step window: min coverage (12-2)*2.44e-4 = 2.44e-3 >
        // 1.8e-3 worst-case differential approx error.
        if (l31 == 0 &&
            ((B2 & 0xFFFFFE00u) - (B1 & 0xFFFFFE00u)) <= (12u << 9)) {
            int slot = atomicAdd(cnt, 1);
            if (slot < LISTCAP)
                list[slot] = (int)(((unsigned int)row << 9) | (unsigned int)idx);
        }
        // out = R(x + R(q - x)); 32 lanes x 2 cols cover the row
        const float2 q2 = ((const float2*)(ET + idx * DIM))[l31];
        const float2 x2 = ((const float2*)(x + row * DIM))[l31];
        float d0 = __fadd_rn(q2.x, -x2.x);
        float d1 = __fadd_rn(q2.y, -x2.y);
        float2 o;
        o.x = __fadd_rn(x2.x, d0);
        o.y = __fadd_rn(x2.y, d1);
        ((float2*)(outp + row * DIM))[l31] = o;
        lsq = fmaf(d0, d0, lsq);
        lsq = fmaf(d1, d1, lsq);
    }
    #pragma unroll
    for (int off = 32; off > 0; off >>= 1) lsq += __shfl_xor(lsq, off, 64);
    if (lane == 0) atomicAdd(loss, lsq * (1.25f / (float)NELEM));
}

// ---- fixup: 8 flagged rows PER WAVE (E read once per 8 rows). z rows
// register-distributed (lane i holds z[i]); broadcasts via shfl. Bit-exact
// numpy emulation: AVX512-pairwise xnorm (shfl tree, same add order),
// sequential-i FMA chains, first-index argmin. Rewrites rows that changed.
__global__ __launch_bounds__(256, 1)
void vq_fixup(const float* __restrict__ x, const float* __restrict__ E,
              const float* __restrict__ ET, const float* __restrict__ en,
              float* __restrict__ outp, float* __restrict__ loss,
              const int* __restrict__ cnt, const int* __restrict__ list) {
    const int tid  = threadIdx.x;
    const int wv   = tid >> 6;
    const int lane = tid & 63;
    int total = *cnt;
    if (total > LISTCAP) total = LISTCAP;
    const int wgid   = blockIdx.x * 4 + wv;
    const int nwaves = gridDim.x * 4;

    // this lane's 8 codes' exact enorm (reused across all rows)
    float enk[8];
    {
        float4 e0 = ((const float4*)(en + lane * 8))[0];
        float4 e1 = ((const float4*)(en + lane * 8))[1];
        enk[0] = e0.x; enk[1] = e0.y; enk[2] = e0.z; enk[3] = e0.w;
        enk[4] = e1.x; enk[5] = e1.y; enk[6] = e1.z; enk[7] = e1.w;
    }

    for (int base = wgid * 8; base < total; base += nwaves * 8) {
        const int nrows = min(8, total - base);
        int ent = 0;
        if (lane < 8 && base + lane < total) ent = list[base + lane];

        // z register-distributed: zreg[r8] = x[row_r8 * 64 + lane]
        float zreg[8];
        #pragma unroll
        for (int r8 = 0; r8 < 8; ++r8) {
            int er = __shfl(ent, r8, 64);
            zreg[r8] = x[(size_t)(er >> 9) * DIM + lane];
        }

        // exact xnorm per row: numpy AVX512 pairwise tree via shuffles
        float xnr[8];
        #pragma unroll
        for (int r8 = 0; r8 < 8; ++r8) {
            float s = __fmul_rn(zreg[r8], zreg[r8]);       // R(z*z) per elem
            int j = lane & 15;
            float a = __fadd_rn(__shfl(s, j, 64),      __shfl(s, j + 16, 64));
            float b = __fadd_rn(__shfl(s, j + 32, 64), __shfl(s, j + 48, 64));
            float v = __fadd_rn(a, b);                     // lane holds v_{lane&15}
            int j8 = lane & 7;
            float u = __fadd_rn(__shfl(v, j8, 64), __shfl(v, j8 + 8, 64));
            int j4 = lane & 3;
            float c = __fadd_rn(__shfl(u, j4, 64), __shfl(u, j4 + 4, 64));
            xnr[r8] = __fadd_rn(__fadd_rn(__shfl(c, 0, 64), __shfl(c, 2, 64)),
                                __fadd_rn(__shfl(c, 1, 64), __shfl(c, 3, 64)));
        }

        // exact sims for 8 rows x this lane's 8 codes; sequential-i chains.
        float acc[8][8];
        #pragma unroll
        for (int r8 = 0; r8 < 8; ++r8)
            #pragma unroll
            for (int j = 0; j < 8; ++j) acc[r8][j] = 0.f;
        const float* Ep = E + lane * 8;
        #pragma unroll 4
        for (int i = 0; i < DIM; ++i) {
            const float4 e0 = ((const float4*)(Ep + (size_t)i * KCODES))[0];
            const float4 e1 = ((const float4*)(Ep + (size_t)i * KCODES))[1];
            float ev[8] = {e0.x, e0.y, e0.z, e0.w, e1.x, e1.y, e1.z, e1.w};
            #pragma unroll
            for (int r8 = 0; r8 < 8; ++r8) {
                const float zi = __shfl(zreg[r8], i, 64);
                #pragma unroll
                for (int j = 0; j < 8; ++j)
                    acc[r8][j] = __fmaf_rn(zi, ev[j], acc[r8][j]);
            }
        }

        // per row: dist, first-index argmin, rewrite if changed
        for (int r8 = 0; r8 < nrows; ++r8) {
            const int er  = __shfl(ent, r8, 64);
            const int row = er >> 9;
            const int old = er & 511;
            float bd = 3.4e38f; int bk = 0;
            #pragma unroll
            for (int j = 0; j < 8; ++j) {
                int k = lane * 8 + j;
                float t1 = __fadd_rn(xnr[r8], enk[j]);
                float d  = __fadd_rn(t1, -2.0f * acc[r8][j]);
                if (d < bd) { bd = d; bk = k; }
            }
            #pragma unroll
            for (int off = 1; off <= 32; off <<= 1) {
                float od = __shfl_xor(bd, off, 64);
                int   ok = __shfl_xor(bk, off, 64);
                if (od < bd || (od == bd && ok < bk)) { bd = od; bk = ok; }
            }
            if (bk != old) {
                const float xl = zreg[r8];              // x[row*64 + lane]
                const float qn = ET[bk * DIM + lane];
                const float qo = ET[old * DIM + lane];
                const float dn = __fadd_rn(qn, -xl);
                const float dd = __fadd_rn(qo, -xl);
                outp[(size_t)row * DIM + lane] = __fadd_rn(xl, dn);
                float dl = __fsub_rn(__fmul_rn(dn, dn), __fmul_rn(dd, dd));
                #pragma unroll
                for (int off = 32; off > 0; off >>= 1) dl += __shfl_xor(dl, off, 64);
                if (lane == 0) atomicAdd(loss, dl * (1.25f / (float)NELEM));
            }
        }
    }
}

extern "C" void kernel_launch(void* const* d_in, const int* in_sizes, int n_in,
                              void* d_out, int out_size, void* d_ws, size_t ws_size,
                              hipStream_t stream) {
    const float* x = (const float*)d_in[0];
    const float* E = (const float*)d_in[1];
    float* out  = (float*)d_out;
    float* loss = out + NELEM;
    float* ws = (float*)d_ws;
    float* ET    = ws + WS_ET;
    float* en    = ws + WS_EN;
    float* en8   = ws + WS_EN8;
    uint4* packH = (uint4*)(ws + WS_PACKH);
    int* cnt  = (int*)(ws + WS_CNT);
    int* list = (int*)(ws + WS_LIST);

    vq_prep<<<2, 256, 0, stream>>>(E, ET, en, en8, loss, cnt);
    vq_pack<<<16, 256, 0, stream>>>(E, packH);
    vq_main<<<2048, 256, 0, stream>>>(x, ET, en8, packH, out, loss, cnt, list);
    vq_fixup<<<512, 256, 0, stream>>>(x, E, ET, en, out, loss, cnt, list);
}

// Round 8
// 225.670 us; speedup vs baseline: 1.1296x; 1.1296x over previous
//
#include <hip/hip_runtime.h>

// VectorQuantizer: x (64,64,64,64) f32, embeddings (64,512) f32
// rows N = 64^3 = 262144, D = 64, K = 512
// out: quantized_st (16777216 f32) ++ loss (1 f32)
//
// Round 8: single-term fp16 MFMA main (A = z_hi fp16 ONLY, B = e_hi fp16).
// Approx error: missing terms z*e_lo + z_lo*e_hi, each sigma ~1.1e-4,
// independent -> 10-sigma differential ~3.2e-3 < 12-step window coverage
// (12-2)*4.88e-4 = 4.88e-3 at dist~8. Near-ties flagged and re-resolved by
// the bit-exact numpy-emulation fixup (absmax 0.0 verified rounds 2-7).
// vs round 6 (113 us): half the MFMAs per t (8 vs 16), half the A-build
// cvts, -32 VGPR (al[] gone) -> more waves/SIMD. 2 tiles/wave (r7's 1-tile
// split regressed: per-wave amortization beats occupancy here).

typedef __attribute__((ext_vector_type(8))) _Float16 f16x8;
typedef __attribute__((ext_vector_type(16))) float f32x16;

#define NROWS   262144
#define DIM     64
#define KCODES  512
#define NELEM   16777216
#define LISTCAP 65536

// ws layout (float offsets)
#define WS_ET     0        // 512*64 code-major embeddings
#define WS_EN     32768    // exact enorm (numpy rounding)
#define WS_EN8    33280    // enorm + 8 (approx domain, keeps d positive)
#define WS_PACKH  33792    // uint4[4096]: e_hi fp16 B-fragments
#define WS_CNT    50176    // flag counter (int)
#define WS_LIST   50192    // flagged rows: (row<<9)|idx

union FragH { uint4 q; f16x8 v; _Float16 u[8]; };

// ---- prep: ET transpose, exact enorm (R(e*e) + sequential adds), enorm+8,
// zero loss + flag counter.
__global__ void vq_prep(const float* __restrict__ E, float* __restrict__ ET,
                        float* __restrict__ en, float* __restrict__ en8,
                        float* __restrict__ loss, int* __restrict__ cnt) {
    int k = blockIdx.x * blockDim.x + threadIdx.x;   // 0..511
    if (k == 0) *loss = 0.f;
    if (k == 1) *cnt = 0;
    float s = 0.f;
    for (int i = 0; i < DIM; ++i) {
        float v = E[i * KCODES + k];
        ET[k * DIM + i] = v;
        s = __fadd_rn(s, __fmul_rn(v, v));
    }
    en[k] = s;
    en8[k] = __fadd_rn(s, 8.0f);
}

// ---- pack e_hi (fp16 RNE) into 32x32x16 B-fragment order:
// frag id = (t*4+c)*64+lane holds B[k = c*16+(lane>>5)*8+j][n = t*32+(lane&31)]
__global__ void vq_pack(const float* __restrict__ E, uint4* __restrict__ packH) {
    const int id = blockIdx.x * 256 + threadIdx.x;   // 0..4095
    const int lane = id & 63;
    const int c = (id >> 6) & 3;
    const int t = id >> 8;
    const int n = t * 32 + (lane & 31);
    const int kb = c * 16 + (lane >> 5) * 8;
    FragH H;
    #pragma unroll
    for (int j = 0; j < 8; ++j)
        H.u[j] = (_Float16)E[(size_t)(kb + j) * KCODES + n];
    packH[id] = H.q;
}

// ---- main: 4 waves x 64 rows = 256 rows/block, grid 1024. No LDS.
// Each wave: TWO 32x32 M-tiles over 16 col-tiles; 8 MFMA per t.
__global__ __launch_bounds__(256)
void vq_main(const float* __restrict__ x, const float* __restrict__ ET,
             const float* __restrict__ en8, const uint4* __restrict__ packH,
             float* __restrict__ outp, float* __restrict__ loss,
             int* __restrict__ cnt, int* __restrict__ list) {
    const int tid  = threadIdx.x;
    const int wv   = tid >> 6;
    const int lane = tid & 63;
    const int h    = lane >> 5;
    const int l31  = lane & 31;
    const size_t rowbase = (size_t)blockIdx.x * 256 + (size_t)wv * 64;

    // A fragments: z_hi fp16 only; A[m=lane&31][k=c*16+h*8+j]
    FragH ah[2][4];
    #pragma unroll
    for (int m = 0; m < 2; ++m) {
        const float* xr = x + (rowbase + m * 32 + l31) * DIM;
        #pragma unroll
        for (int c = 0; c < 4; ++c) {
            const float* xp = xr + c * 16 + h * 8;
            float4 p0 = *(const float4*)xp;
            float4 p1 = *(const float4*)(xp + 4);
            ah[m][c].u[0] = (_Float16)p0.x; ah[m][c].u[1] = (_Float16)p0.y;
            ah[m][c].u[2] = (_Float16)p0.z; ah[m][c].u[3] = (_Float16)p0.w;
            ah[m][c].u[4] = (_Float16)p1.x; ah[m][c].u[5] = (_Float16)p1.y;
            ah[m][c].u[6] = (_Float16)p1.z; ah[m][c].u[7] = (_Float16)p1.w;
        }
    }

    float en8v[16];
    #pragma unroll
    for (int t = 0; t < 16; ++t) en8v[t] = en8[t * 32 + l31];

    unsigned int b1[2][16], b2[2][16];               // per-row-slot top-2 keys
    #pragma unroll
    for (int m = 0; m < 2; ++m)
        #pragma unroll
        for (int r = 0; r < 16; ++r) { b1[m][r] = 0xFFFFFFFFu; b2[m][r] = 0xFFFFFFFFu; }

    // Register double-buffer: prefetch t+1's B-fragments before t's MFMAs.
    FragH bh[4], bn[4];
    #pragma unroll
    for (int c = 0; c < 4; ++c) bh[c].q = packH[c * 64 + lane];

    for (int t = 0; t < 16; ++t) {
        if (t < 15) {
            #pragma unroll
            for (int c = 0; c < 4; ++c)
                bn[c].q = packH[((t + 1) * 4 + c) * 64 + lane];   // L1/L2-hot
        }
        f32x16 A0, A1;
        #pragma unroll
        for (int r = 0; r < 16; ++r) { A0[r] = 0.f; A1[r] = 0.f; }
        #pragma unroll
        for (int c = 0; c < 4; ++c) {                    // z_hi * e_hi only
            A0 = __builtin_amdgcn_mfma_f32_32x32x16_f16(ah[0][c].v, bh[c].v, A0, 0, 0, 0);
            A1 = __builtin_amdgcn_mfma_f32_32x32x16_f16(ah[1][c].v, bh[c].v, A1, 0, 0, 0);
        }
        // keys: d = enorm+8 - 2*sim > 0; (bits & ~511) | col sorts by dist
        const unsigned int colv = (unsigned int)(t * 32 + l31);
        #pragma unroll
        for (int r = 0; r < 16; ++r) {
            {
                float d = fmaf(-2.f, A0[r], en8v[t]);
                unsigned int key = (__float_as_uint(d) & 0xFFFFFE00u) | colv;
                unsigned int n1 = min(key, b1[0][r]);
                unsigned int mx = max(key, b1[0][r]);
                b2[0][r] = min(b2[0][r], mx);
                b1[0][r] = n1;
            }
            {
                float d = fmaf(-2.f, A1[r], en8v[t]);
                unsigned int key = (__float_as_uint(d) & 0xFFFFFE00u) | colv;
                unsigned int n1 = min(key, b1[1][r]);
                unsigned int mx = max(key, b1[1][r]);
                b2[1][r] = min(b2[1][r], mx);
                b1[1][r] = n1;
            }
        }
        #pragma unroll
        for (int c = 0; c < 4; ++c) bh[c] = bn[c];
    }

    // merge top-2 across the 32-lane half-group; C row = (r&3)+8*(r>>2)+4*h
    float lsq = 0.f;
    #pragma unroll
    for (int m = 0; m < 2; ++m) {
        #pragma unroll
        for (int r = 0; r < 16; ++r) {
            unsigned int B1 = b1[m][r], B2 = b2[m][r];
            #pragma unroll
            for (int off = 1; off <= 16; off <<= 1) {
                unsigned int o1 = (unsigned int)__shfl_xor((int)B1, off, 64);
                unsigned int o2 = (unsigned int)__shfl_xor((int)B2, off, 64);
                unsigned int n1 = min(B1, o1);
                unsigned int mx = max(B1, o1);
                B2 = min(min(B2, o2), mx);
                B1 = n1;
            }
            const int idx = (int)(B1 & 511u);
            const int rowl = (r & 3) + 8 * (r >> 2) + 4 * h;
            const size_t row = rowbase + m * 32 + rowl;
            // 12-step window: coverage (12-2)*4.88e-4 = 4.88e-3 > 3.2e-3
            // worst-case differential approx error (z*e_lo + z_lo*e_hi terms).
            if (l31 == 0 &&
                ((B2 & 0xFFFFFE00u) - (B1 & 0xFFFFFE00u)) <= (12u << 9)) {
                int slot = atomicAdd(cnt, 1);
                if (slot < LISTCAP)
                    list[slot] = (int)(((unsigned int)row << 9) | (unsigned int)idx);
            }
            // out = R(x + R(q - x)); 32 lanes x 2 cols cover the row
            const float2 q2 = ((const float2*)(ET + idx * DIM))[l31];
            const float2 x2 = ((const float2*)(x + row * DIM))[l31];
            float d0 = __fadd_rn(q2.x, -x2.x);
            float d1 = __fadd_rn(q2.y, -x2.y);
            float2 o;
            o.x = __fadd_rn(x2.x, d0);
            o.y = __fadd_rn(x2.y, d1);
            ((float2*)(outp + row * DIM))[l31] = o;
            lsq = fmaf(d0, d0, lsq);
            lsq = fmaf(d1, d1, lsq);
        }
    }
    #pragma unroll
    for (int off = 32; off > 0; off >>= 1) lsq += __shfl_xor(lsq, off, 64);
    if (lane == 0) atomicAdd(loss, lsq * (1.25f / (float)NELEM));
}

// ---- fixup: 8 flagged rows PER WAVE (E read once per 8 rows). z rows
// register-distributed (lane i holds z[i]); broadcasts via shfl. Bit-exact
// numpy emulation: AVX512-pairwise xnorm (shfl tree, same add order),
// sequential-i FMA chains, first-index argmin. Rewrites rows that changed.
__global__ __launch_bounds__(256, 1)
void vq_fixup(const float* __restrict__ x, const float* __restrict__ E,
              const float* __restrict__ ET, const float* __restrict__ en,
              float* __restrict__ outp, float* __restrict__ loss,
              const int* __restrict__ cnt, const int* __restrict__ list) {
    const int tid  = threadIdx.x;
    const int wv   = tid >> 6;
    const int lane = tid & 63;
    int total = *cnt;
    if (total > LISTCAP) total = LISTCAP;
    const int wgid   = blockIdx.x * 4 + wv;
    const int nwaves = gridDim.x * 4;

    // this lane's 8 codes' exact enorm (reused across all rows)
    float enk[8];
    {
        float4 e0 = ((const float4*)(en + lane * 8))[0];
        float4 e1 = ((const float4*)(en + lane * 8))[1];
        enk[0] = e0.x; enk[1] = e0.y; enk[2] = e0.z; enk[3] = e0.w;
        enk[4] = e1.x; enk[5] = e1.y; enk[6] = e1.z; enk[7] = e1.w;
    }

    for (int base = wgid * 8; base < total; base += nwaves * 8) {
        const int nrows = min(8, total - base);
        int ent = 0;
        if (lane < 8 && base + lane < total) ent = list[base + lane];

        // z register-distributed: zreg[r8] = x[row_r8 * 64 + lane]
        float zreg[8];
        #pragma unroll
        for (int r8 = 0; r8 < 8; ++r8) {
            int er = __shfl(ent, r8, 64);
            zreg[r8] = x[(size_t)(er >> 9) * DIM + lane];
        }

        // exact xnorm per row: numpy AVX512 pairwise tree via shuffles
        float xnr[8];
        #pragma unroll
        for (int r8 = 0; r8 < 8; ++r8) {
            float s = __fmul_rn(zreg[r8], zreg[r8]);       // R(z*z) per elem
            int j = lane & 15;
            float a = __fadd_rn(__shfl(s, j, 64),      __shfl(s, j + 16, 64));
            float b = __fadd_rn(__shfl(s, j + 32, 64), __shfl(s, j + 48, 64));
            float v = __fadd_rn(a, b);                     // lane holds v_{lane&15}
            int j8 = lane & 7;
            float u = __fadd_rn(__shfl(v, j8, 64), __shfl(v, j8 + 8, 64));
            int j4 = lane & 3;
            float c = __fadd_rn(__shfl(u, j4, 64), __shfl(u, j4 + 4, 64));
            xnr[r8] = __fadd_rn(__fadd_rn(__shfl(c, 0, 64), __shfl(c, 2, 64)),
                                __fadd_rn(__shfl(c, 1, 64), __shfl(c, 3, 64)));
        }

        // exact sims for 8 rows x this lane's 8 codes; sequential-i chains.
        float acc[8][8];
        #pragma unroll
        for (int r8 = 0; r8 < 8; ++r8)
            #pragma unroll
            for (int j = 0; j < 8; ++j) acc[r8][j] = 0.f;
        const float* Ep = E + lane * 8;
        #pragma unroll 4
        for (int i = 0; i < DIM; ++i) {
            const float4 e0 = ((const float4*)(Ep + (size_t)i * KCODES))[0];
            const float4 e1 = ((const float4*)(Ep + (size_t)i * KCODES))[1];
            float ev[8] = {e0.x, e0.y, e0.z, e0.w, e1.x, e1.y, e1.z, e1.w};
            #pragma unroll
            for (int r8 = 0; r8 < 8; ++r8) {
                const float zi = __shfl(zreg[r8], i, 64);
                #pragma unroll
                for (int j = 0; j < 8; ++j)
                    acc[r8][j] = __fmaf_rn(zi, ev[j], acc[r8][j]);
            }
        }

        // per row: dist, first-index argmin, rewrite if changed
        for (int r8 = 0; r8 < nrows; ++r8) {
            const int er  = __shfl(ent, r8, 64);
            const int row = er >> 9;
            const int old = er & 511;
            float bd = 3.4e38f; int bk = 0;
            #pragma unroll
            for (int j = 0; j < 8; ++j) {
                int k = lane * 8 + j;
                float t1 = __fadd_rn(xnr[r8], enk[j]);
                float d  = __fadd_rn(t1, -2.0f * acc[r8][j]);
                if (d < bd) { bd = d; bk = k; }
            }
            #pragma unroll
            for (int off = 1; off <= 32; off <<= 1) {
                float od = __shfl_xor(bd, off, 64);
                int   ok = __shfl_xor(bk, off, 64);
                if (od < bd || (od == bd && ok < bk)) { bd = od; bk = ok; }
            }
            if (bk != old) {
                const float xl = zreg[r8];              // x[row*64 + lane]
                const float qn = ET[bk * DIM + lane];
                const float qo = ET[old * DIM + lane];
                const float dn = __fadd_rn(qn, -xl);
                const float dd = __fadd_rn(qo, -xl);
                outp[(size_t)row * DIM + lane] = __fadd_rn(xl, dn);
                float dl = __fsub_rn(__fmul_rn(dn, dn), __fmul_rn(dd, dd));
                #pragma unroll
                for (int off = 32; off > 0; off >>= 1) dl += __shfl_xor(dl, off, 64);
                if (lane == 0) atomicAdd(loss, dl * (1.25f / (float)NELEM));
            }
        }
    }
}

extern "C" void kernel_launch(void* const* d_in, const int* in_sizes, int n_in,
                              void* d_out, int out_size, void* d_ws, size_t ws_size,
                              hipStream_t stream) {
    const float* x = (const float*)d_in[0];
    const float* E = (const float*)d_in[1];
    float* out  = (float*)d_out;
    float* loss = out + NELEM;
    float* ws = (float*)d_ws;
    float* ET    = ws + WS_ET;
    float* en    = ws + WS_EN;
    float* en8   = ws + WS_EN8;
    uint4* packH = (uint4*)(ws + WS_PACKH);
    int* cnt  = (int*)(ws + WS_CNT);
    int* list = (int*)(ws + WS_LIST);

    vq_prep<<<2, 256, 0, stream>>>(E, ET, en, en8, loss, cnt);
    vq_pack<<<16, 256, 0, stream>>>(E, packH);
    vq_main<<<1024, 256, 0, stream>>>(x, ET, en8, packH, out, loss, cnt, list);
    vq_fixup<<<512, 256, 0, stream>>>(x, E, ET, en, out, loss, cnt, list);
}